// Round 11
// baseline (464.788 us; speedup 1.0000x reference)
//
#include <hip/hip_runtime.h>
#include <math.h>

#define WAVE 64
#define NC 21

__device__ __forceinline__ unsigned f32_ord(float f) {
    unsigned u = __float_as_uint(f);
    return (u & 0x80000000u) ? ~u : (u | 0x80000000u);
}

__device__ __forceinline__ int wave_sum_i32(int v) {
#pragma unroll
    for (int off = 32; off >= 1; off >>= 1)
        v += __shfl_xor(v, off, WAVE);
    return v;
}

__device__ __forceinline__ unsigned long long wave_min_u64(unsigned long long v) {
#pragma unroll
    for (int off = 32; off >= 1; off >>= 1) {
        unsigned long long o = __shfl_xor(v, off, WAVE);
        v = (o < v) ? o : v;
    }
    return v;
}

__device__ __forceinline__ float wave_max_f32(float v) {
#pragma unroll
    for (int off = 32; off >= 1; off >>= 1)
        v = fmaxf(v, __shfl_xor(v, off, WAVE));
    return v;
}

__device__ __forceinline__ float wave_sum_f32(float v) {
#pragma unroll
    for (int off = 32; off >= 1; off >>= 1)
        v += __shfl_xor(v, off, WAVE);
    return v;
}

// Full bitonic sort of 64 u64 keys (one per lane), ascending. (validated R7)
__device__ __forceinline__ unsigned long long bitonic_sort64(
    unsigned long long v, int lane)
{
#pragma unroll
    for (int k = 2; k <= 64; k <<= 1) {
#pragma unroll
        for (int j = k >> 1; j > 0; j >>= 1) {
            unsigned long long o = __shfl_xor(v, j, WAVE);
            bool take_min = (((lane & j) == 0) == ((lane & k) == 0));
            unsigned long long mn = (v < o) ? v : o;
            unsigned long long mx = (v < o) ? o : v;
            v = take_min ? mn : mx;
        }
    }
    return v;
}

// h asc, c asc -> asc smallest-64 of union. (validated R7)
__device__ __forceinline__ unsigned long long bitonic_merge_keep_low(
    unsigned long long h, unsigned long long c, int lane)
{
    unsigned long long cr = __shfl(c, 63 - lane, WAVE);
    unsigned long long v = (h < cr) ? h : cr;
#pragma unroll
    for (int j = 32; j > 0; j >>= 1) {
        unsigned long long o = __shfl_xor(v, j, WAVE);
        bool take_min = ((lane & j) == 0);
        unsigned long long mn = (v < o) ? v : o;
        unsigned long long mx = (v < o) ? o : v;
        v = take_min ? mn : mx;
    }
    return v;
}

__device__ __forceinline__ unsigned long long cand_u64(
    const float4* __restrict__ spts, int ch, int lane,
    float qx, float qy, float qz, float nq)
{
    int g = ch * 64 + lane;
    float4 p = spts[g];
    float dot = qx * p.x + qy * p.y + qz * p.z;
    unsigned o = f32_ord(-2.0f * dot + nq + p.w);   // identical expr R1-R9
    return ((unsigned long long)o << 32) | (unsigned)g;
}

// ---------------------------------------------------------------------------
// Wave-local exact top-NS set selection over NI LDS-resident points.
// No barriers, no LDS atomics. sel[0..NS) <- selected global indices.
// Tie-break identical to jax.lax.top_k via u64 (key,idx) order.
// ---------------------------------------------------------------------------
template <int NI, int NS>
__device__ __forceinline__ void wave_select(
    const float4* __restrict__ spts,
    float qx, float qy, float qz, float nq,
    int* __restrict__ sel,                    // LDS, this wave, [64]
    unsigned long long* __restrict__ band,    // LDS, this wave, [128]
    int lane)
{
    constexpr int NCH = NI / 64;
    const unsigned long long lm = (1ull << lane) - 1ull;

    // pass 1: per-lane min (u64) over its NCH candidates
    unsigned long long mnu = ~0ull;
#pragma unroll 4
    for (int ch = 0; ch < NCH; ++ch) {
        unsigned long long u = cand_u64(spts, ch, lane, qx, qy, qz, nq);
        mnu = (u < mnu) ? u : mnu;
    }
    unsigned long long S = bitonic_sort64(mnu, lane);   // exact order stats

    // probes: s_j = NS-1 - j*D (invalid if < 0). count(<=S[NS-1]) >= NS always.
    constexpr int D = (NS >= 8) ? (NS / 8) : 1;
    unsigned long long tj[6];
    int pj[6];
#pragma unroll
    for (int j = 0; j < 6; ++j) {
        pj[j] = NS - 1 - j * D;
        tj[j] = __shfl(S, (pj[j] >= 0) ? pj[j] : 0, WAVE);
    }

    // pass 2: membership bitmask per probe (fused, one LDS sweep)
    unsigned long long msk[6] = {0ull, 0ull, 0ull, 0ull, 0ull, 0ull};
#pragma unroll 4
    for (int ch = 0; ch < NCH; ++ch) {
        unsigned long long u = cand_u64(spts, ch, lane, qx, qy, qz, nq);
        unsigned long long bit = 1ull << ch;
#pragma unroll
        for (int j = 0; j < 6; ++j)
            msk[j] |= (u <= tj[j]) ? bit : 0ull;
    }
    int c[6];
#pragma unroll
    for (int j = 0; j < 6; ++j) {
        c[j] = wave_sum_i32(__popcll(msk[j]));
        if (pj[j] < 0) c[j] = -1;               // invalid probe
    }
    int js = 0;                                  // max j with c[j] >= NS
#pragma unroll
    for (int j = 1; j < 6; ++j) if (c[j] >= NS) js = j;

    int Cb = 0;
    unsigned long long mA = 0ull;
    if (js < 5 && pj[js + 1] >= 0) { Cb = c[js + 1]; mA = msk[js + 1]; }
    // Cb < NS (js maximal-valid) => {<=tj[js+1]} is exactly the top-Cb set.

    unsigned long long bmask = msk[js] & ~mA;
    int bandM = c[js] - Cb;
    int R = NS - Cb;                             // >= 1

    if (Cb > 0) {                                // compact A (idx only)
        int base = 0;
#pragma unroll 4
        for (int ch = 0; ch < NCH; ++ch) {
            bool a = (mA >> ch) & 1ull;
            unsigned long long mk = __ballot(a);
            if (a) sel[base + __popcll(mk & lm)] = ch * 64 + lane;
            base += __popcll(mk);
        }
    }

    if (bandM == R) {                            // whole band selected
        int base = Cb;
#pragma unroll 4
        for (int ch = 0; ch < NCH; ++ch) {
            bool s = (bmask >> ch) & 1ull;
            unsigned long long mk = __ballot(s);
            if (s) sel[base + __popcll(mk & lm)] = ch * 64 + lane;
            base += __popcll(mk);
        }
    } else if (bandM <= 128) {
        int base = 0;
#pragma unroll 4
        for (int ch = 0; ch < NCH; ++ch) {
            bool s = (bmask >> ch) & 1ull;
            unsigned long long mk = __ballot(s);
            if (s) band[base + __popcll(mk & lm)] =
                       cand_u64(spts, ch, lane, qx, qy, qz, nq);
            base += __popcll(mk);
        }
        __threadfence_block();
        unsigned long long v0 = (lane < bandM) ? band[lane] : ~0ull;
        v0 = bitonic_sort64(v0, lane);
        if (bandM > 64) {
            unsigned long long v1 = (64 + lane < bandM) ? band[64 + lane] : ~0ull;
            v1 = bitonic_sort64(v1, lane);
            v0 = bitonic_merge_keep_low(v0, v1, lane);
        }
        if (lane < R) sel[Cb + lane] = (int)(unsigned)v0;
    } else {
        // exact fallback (pathological tie mass): NS-round extraction
        unsigned long long cons = 0ull;
        for (int r = 0; r < NS; ++r) {
            unsigned long long best = ~0ull;
#pragma unroll 4
            for (int ch = 0; ch < NCH; ++ch) {
                if (!((cons >> ch) & 1ull)) {
                    unsigned long long u = cand_u64(spts, ch, lane, qx, qy, qz, nq);
                    best = (u < best) ? u : best;
                }
            }
            best = wave_min_u64(best);
            unsigned gi = (unsigned)best;
            if ((gi & 63u) == (unsigned)lane) cons |= 1ull << (gi >> 6);
            if (lane == 0) sel[r] = (int)gi;
        }
    }
    __threadfence_block();                       // sel visible to this wave
}

// ---------------------------------------------------------------------------
template <int NI, int NS>
__device__ __forceinline__ void boundary_epilogue(
    const float* __restrict__ feat, const int* __restrict__ lbl,
    double* __restrict__ pos, double* __restrict__ neg, int* __restrict__ anyf,
    int b, int qi, int lane, int nb)
{
    int center = lbl[(long)b * NI + qi];
    bool m = false;
    float dj = -INFINITY;
    if (lane < NS) {
        m = (lbl[(long)b * NI + nb] == center);
        const float4* fq = (const float4*)(feat + ((long)b * NI + qi) * 32);
        const float4* fn = (const float4*)(feat + ((long)b * NI + nb) * 32);
        float s = 0.f;
#pragma unroll
        for (int d = 0; d < 8; ++d) {
            float4 a = fq[d], c = fn[d];
            float d0 = a.x - c.x, d1 = a.y - c.y;
            float d2 = a.z - c.z, d3 = a.w - c.w;
            s += d0 * d0 + d1 * d1 + d2 * d2 + d3 * d3;
        }
        dj = -sqrtf(s + 1e-6f);
    }
    unsigned long long mb = __ballot(m);
    int cnt = __popcll(mb);
    float mxv = wave_max_f32(dj);
    float ej = 0.f, pj = 0.f;
    if (lane < NS) {
        ej = expf(dj - mxv);                    // TEMPERATURE == 1
        pj = m ? ej : 0.f;
    }
    float se = wave_sum_f32(ej);
    float sp = wave_sum_f32(pj);
    bool pm = (cnt > 0) && (cnt < NS);
    if (pm && lane == 0) {
        atomicAdd(pos, (double)sp);
        atomicAdd(neg, (double)se);
        *anyf = 1;
    }
}

// per-wave KNN-label epilogue (validated R4-R9)
template <int K>
__device__ __forceinline__ void knn_epilogue(
    const int* __restrict__ rl, int* __restrict__ out,
    long b, int out_idx, int lane, const int* __restrict__ sel)
{
    int lb = (lane < K) ? rl[b * 4096 + sel[lane]] : -1;
    int cnt = 0;
#pragma unroll
    for (int k = 0; k < K; ++k) {
        int lk = __shfl(lb, k, WAVE);
        cnt += (lk == lane) ? 1 : 0;
    }
    int key = (lane < NC) ? ((cnt << 8) | (255 - lane)) : 0;
#pragma unroll
    for (int off = 32; off >= 1; off >>= 1) {
        int o = __shfl_xor(key, off, WAVE);
        key = (o > key) ? o : key;
    }
    if (lane == 0) out[out_idx] = 255 - (key & 255);
}

struct Shm {
    float4 pts[4096];
    int sel[4][64];
    unsigned long long band[4][128];
};

// ---------------------------------------------------------------------------
// boundary: one wave per query, 16 queries per block (4 per wave).
// Sections: level0 (4096,64), level1 (1024,32), level2 (256,16) via
// wave_select; levels 3,4 direct bitonic.
// ---------------------------------------------------------------------------
template <int NI, int NS>
__device__ __forceinline__ void bnd_sec(
    int sblk, const float4* __restrict__ pk, const float* __restrict__ qc,
    const float* __restrict__ feat, const int* __restrict__ lbl,
    double* pos, double* neg, int* anyf, Shm& shm, int tid)
{
    int b = (sblk * 16) / NI;                   // all NI divisible by 16
    for (int i = tid; i < NI; i += 256) shm.pts[i] = pk[(long)b * NI + i];
    __syncthreads();                            // the ONLY barrier
    int w = tid >> 6, lane = tid & 63;
    int q0 = sblk * 16 + w * 4;
#pragma unroll 1
    for (int i = 0; i < 4; ++i) {
        int q = q0 + i;
        int qi = q - b * NI;
        const float* qp = qc + ((long)b * NI + qi) * 3;
        float qx = qp[0], qy = qp[1], qz = qp[2];
        float nq = qx * qx + qy * qy + qz * qz;
        wave_select<NI, NS>(shm.pts, qx, qy, qz, nq,
                            shm.sel[w], shm.band[w], lane);
        boundary_epilogue<NI, NS>(feat, lbl, pos, neg, anyf, b, qi, lane,
                                  (lane < NS) ? shm.sel[w][lane] : 0);
    }
}

template <int NI, int NS>
__device__ __forceinline__ void small_sec(
    int sblk, const float4* __restrict__ pk, const float* __restrict__ qc,
    const float* __restrict__ feat, const int* __restrict__ lbl,
    double* pos, double* neg, int* anyf, int tid)
{
    int w = tid >> 6, lane = tid & 63;
#pragma unroll 1
    for (int i = 0; i < 4; ++i) {
        int q = sblk * 16 + w * 4 + i;
        int b = q / NI, qi = q - b * NI;
        const float* qp = qc + ((long)b * NI + qi) * 3;
        float qx = qp[0], qy = qp[1], qz = qp[2];
        float nq = qx * qx + qy * qy + qz * qz;
        unsigned long long p = ~0ull;
        if (lane < NI) {
            float4 P = pk[(long)b * NI + lane];
            float dot = qx * P.x + qy * P.y + qz * P.z;
            unsigned o = f32_ord(-2.0f * dot + nq + P.w);
            p = ((unsigned long long)o << 32) | (unsigned)lane;
        }
        unsigned long long h = bitonic_sort64(p, lane);
        boundary_epilogue<NI, NS>(feat, lbl, pos, neg, anyf, b, qi, lane,
                                  (int)(unsigned)h);
    }
}

__global__ __launch_bounds__(256) void boundary_fused(
    const float4* __restrict__ p0, const float4* __restrict__ p1,
    const float4* __restrict__ p2, const float4* __restrict__ p3,
    const float4* __restrict__ p4,
    const float* __restrict__ c0, const float* __restrict__ c1,
    const float* __restrict__ c2, const float* __restrict__ c3,
    const float* __restrict__ c4,
    const float* __restrict__ f0, const float* __restrict__ f1,
    const float* __restrict__ f2, const float* __restrict__ f3,
    const float* __restrict__ f4,
    const int* __restrict__ labels, const int* __restrict__ lbl1,
    const int* __restrict__ lbl2, const int* __restrict__ lbl3,
    const int* __restrict__ lbl4,
    double* __restrict__ posA, double* __restrict__ negA,
    int* __restrict__ anyA, int B)
{
    __shared__ Shm shm;
    int blk = blockIdx.x, tid = threadIdx.x;
    int s0 = B * 4096 / 16, s1 = s0 + B * 1024 / 16, s2 = s1 + B * 256 / 16;
    int s3 = s2 + B * 64 / 16, s4 = s3 + B * 16 / 16;
    if (blk < s0)
        bnd_sec<4096, 64>(blk, p0, c0, f0, labels, posA+0, negA+0, anyA+0, shm, tid);
    else if (blk < s1)
        bnd_sec<1024, 32>(blk - s0, p1, c1, f1, lbl1, posA+1, negA+1, anyA+1, shm, tid);
    else if (blk < s2)
        bnd_sec<256, 16>(blk - s1, p2, c2, f2, lbl2, posA+2, negA+2, anyA+2, shm, tid);
    else if (blk < s3)
        small_sec<64, 8>(blk - s2, p3, c3, f3, lbl3, posA+3, negA+3, anyA+3, tid);
    else if (blk < s4)
        small_sec<16, 4>(blk - s3, p4, c4, f4, lbl4, posA+4, negA+4, anyA+4, tid);
}

// ---------------------------------------------------------------------------
template <int NQ, int K>
__device__ __forceinline__ void knn_sec(
    int sblk, const float4* __restrict__ pk0, const float* __restrict__ qc,
    const int* __restrict__ rl, int* __restrict__ out, Shm& shm, int tid)
{
    int b = (sblk * 16) / NQ;
    for (int i = tid; i < 4096; i += 256) shm.pts[i] = pk0[(long)b * 4096 + i];
    __syncthreads();
    int w = tid >> 6, lane = tid & 63;
    int q0 = sblk * 16 + w * 4;
#pragma unroll 1
    for (int i = 0; i < 4; ++i) {
        int q = q0 + i;
        int qi = q - b * NQ;
        const float* qp = qc + ((long)b * NQ + qi) * 3;
        float qx = qp[0], qy = qp[1], qz = qp[2];
        float nq = qx * qx + qy * qy + qz * qz;
        wave_select<4096, K>(shm.pts, qx, qy, qz, nq,
                             shm.sel[w], shm.band[w], lane);
        knn_epilogue<K>(rl, out, b, (int)((long)b * NQ + qi), lane, shm.sel[w]);
    }
}

__global__ __launch_bounds__(256) void knn_fused(
    const float* __restrict__ c1, const float* __restrict__ c2,
    const float* __restrict__ c3, const float* __restrict__ c4,
    const float4* __restrict__ pk0, const int* __restrict__ labels,
    int* __restrict__ lbl1, int* __restrict__ lbl2,
    int* __restrict__ lbl3, int* __restrict__ lbl4, int B)
{
    __shared__ Shm shm;
    int blk = blockIdx.x, tid = threadIdx.x;
    int n1 = B * 1024 / 16, n2 = n1 + B * 256 / 16;
    int n3 = n2 + B * 64 / 16, n4 = n3 + B * 16 / 16;
    if (blk < n1)      knn_sec<1024, 4>(blk,      pk0, c1, labels, lbl1, shm, tid);
    else if (blk < n2) knn_sec<256,  8>(blk - n1, pk0, c2, labels, lbl2, shm, tid);
    else if (blk < n3) knn_sec<64,  12>(blk - n2, pk0, c3, labels, lbl3, shm, tid);
    else if (blk < n4) knn_sec<16,  16>(blk - n3, pk0, c4, labels, lbl4, shm, tid);
}

// ---------------------------------------------------------------------------
__global__ __launch_bounds__(256) void pack_kernel(
    const float* __restrict__ c0, const float* __restrict__ c1,
    const float* __restrict__ c2, const float* __restrict__ c3,
    const float* __restrict__ c4,
    float4* __restrict__ p0, float4* __restrict__ p1,
    float4* __restrict__ p2, float4* __restrict__ p3,
    float4* __restrict__ p4,
    double* __restrict__ posA, double* __restrict__ negA,
    int* __restrict__ anyA, int B)
{
    int idx = blockIdx.x * 256 + threadIdx.x;
    if (idx < 5) { posA[idx] = 0.0; negA[idx] = 0.0; anyA[idx] = 0; }
    int s0 = B * 4096, s1 = s0 + B * 1024, s2 = s1 + B * 256;
    int s3 = s2 + B * 64, s4 = s3 + B * 16;
    const float* src; float4* dst; int i;
    if (idx < s0)      { src = c0; dst = p0; i = idx; }
    else if (idx < s1) { src = c1; dst = p1; i = idx - s0; }
    else if (idx < s2) { src = c2; dst = p2; i = idx - s1; }
    else if (idx < s3) { src = c3; dst = p3; i = idx - s2; }
    else if (idx < s4) { src = c4; dst = p4; i = idx - s3; }
    else return;
    float x = src[3 * i], y = src[3 * i + 1], z = src[3 * i + 2];
    dst[i] = make_float4(x, y, z, x * x + y * y + z * z);
}

__global__ void finalize_kernel(const double* __restrict__ pos,
                                const double* __restrict__ neg,
                                const int* __restrict__ anyf,
                                float* __restrict__ out) {
    if (threadIdx.x == 0 && blockIdx.x == 0) {
        float loss = 0.f;
        for (int i = 0; i < 5; ++i) {
            if (anyf[i]) {
                float p = (float)pos[i];
                float n = (float)neg[i];
                loss += -logf(p / (n + 1e-6f));
            }
        }
        out[0] = loss;
    }
}

extern "C" void kernel_launch(void* const* d_in, const int* in_sizes, int n_in,
                              void* d_out, int out_size, void* d_ws, size_t ws_size,
                              hipStream_t stream) {
    (void)out_size; (void)ws_size;
    const int* labels = (const int*)d_in[0];
    const float* coord[5];
    const float* feat[5];
    bool interleaved = (n_in >= 3 && in_sizes[2] == 2 * 4096 * 32);
    if (interleaved) {
        for (int i = 0; i < 5; ++i) {
            coord[i] = (const float*)d_in[1 + 2 * i];
            feat[i]  = (const float*)d_in[2 + 2 * i];
        }
    } else {
        for (int i = 0; i < 5; ++i) {
            coord[i] = (const float*)d_in[1 + i];
            feat[i]  = (const float*)d_in[6 + i];
        }
    }
    int B = in_sizes[0] / 4096;   // = 2

    char* ws = (char*)d_ws;
    double* posA = (double*)ws;
    double* negA = posA + 5;
    int* anyA = (int*)(negA + 5);
    int* lbl1 = anyA + 8;
    int* lbl2 = lbl1 + B * 1024;
    int* lbl3 = lbl2 + B * 256;
    int* lbl4 = lbl3 + B * 64;
    size_t off = 112 + (size_t)B * (1024 + 256 + 64 + 16) * 4;
    off = (off + 15) & ~(size_t)15;
    float4* pk0 = (float4*)(ws + off); off += (size_t)B * 4096 * 16;
    float4* pk1 = (float4*)(ws + off); off += (size_t)B * 1024 * 16;
    float4* pk2 = (float4*)(ws + off); off += (size_t)B * 256 * 16;
    float4* pk3 = (float4*)(ws + off); off += (size_t)B * 64 * 16;
    float4* pk4 = (float4*)(ws + off);

    int tot = B * (4096 + 1024 + 256 + 64 + 16);
    hipLaunchKernelGGL(pack_kernel, dim3((tot + 255) / 256), dim3(256), 0, stream,
                       coord[0], coord[1], coord[2], coord[3], coord[4],
                       pk0, pk1, pk2, pk3, pk4, posA, negA, anyA, B);

    int knn_blocks = B * (1024 + 256 + 64 + 16) / 16;
    hipLaunchKernelGGL(knn_fused, dim3(knn_blocks), dim3(256), 0, stream,
                       coord[1], coord[2], coord[3], coord[4],
                       pk0, labels, lbl1, lbl2, lbl3, lbl4, B);

    int bnd_blocks = B * (4096 + 1024 + 256 + 64 + 16) / 16;
    hipLaunchKernelGGL(boundary_fused, dim3(bnd_blocks), dim3(256), 0, stream,
                       pk0, pk1, pk2, pk3, pk4,
                       coord[0], coord[1], coord[2], coord[3], coord[4],
                       feat[0], feat[1], feat[2], feat[3], feat[4],
                       labels, lbl1, lbl2, lbl3, lbl4,
                       posA, negA, anyA, B);

    hipLaunchKernelGGL(finalize_kernel, dim3(1), dim3(1), 0, stream,
                       posA, negA, anyA, (float*)d_out);
}